// Round 1
// baseline (607.641 us; speedup 1.0000x reference)
//
#include <hip/hip_runtime.h>
#include <math.h>

#define Bb 8
#define Tt 4
#define Ll 512
#define Dd 512
#define Hh 8
#define HDd 64
#define Mm (Bb*Tt*Ll)   // 16384 rows

// ---------------- GEMM (f32, NT: A row-major MxK, W row-major NxK) ----------------
// 128x128 tile, BK=16, 256 threads, 8x8 per thread (split as 2x2 of 4x4 quads).

struct GemmArgs {
  const float* A;
  const float* W0; const float* W1; const float* W2;
  const float* g0; const float* b0; const float* rm0; const float* rv0;
  const float* g1; const float* b1; const float* rm1; const float* rv1;
  const float* g2; const float* b2; const float* rm2; const float* rv2;
  const float* bias;      // MODE==1 only
  float* o0; float* o1; float* o2;
};

// MODE 0: fused QKV (grid.x = 12 col-tiles: 0-3 q, 4-7 k, 8-11 v)
//   q: y = acc*S+Sh (store pre-LIF linear)
//   k: relu
//   v: ternary {-1,0,+1}
// MODE 1: O-proj (grid.x = 4): y = (acc + bias)*S + Sh  (store pre-LIF linear)
template<int MODE>
__global__ __launch_bounds__(256, 4)
void gemm_k(GemmArgs ar) {
  __shared__ float As[16][132];
  __shared__ float Bs[16][132];

  const int tid = threadIdx.x;
  const int bx = blockIdx.x, by = blockIdx.y;
  const int seg = (MODE == 0) ? (bx >> 2) : 0;
  const int lc0 = (MODE == 0) ? ((bx & 3) << 7) : (bx << 7);

  const float* Wsel = (MODE == 0) ? (seg == 0 ? ar.W0 : (seg == 1 ? ar.W1 : ar.W2)) : ar.W0;
  const float* gp  = (seg == 0 ? ar.g0  : (seg == 1 ? ar.g1  : ar.g2));
  const float* bp  = (seg == 0 ? ar.b0  : (seg == 1 ? ar.b1  : ar.b2));
  const float* rmp = (seg == 0 ? ar.rm0 : (seg == 1 ? ar.rm1 : ar.rm2));
  const float* rvp = (seg == 0 ? ar.rv0 : (seg == 1 ? ar.rv1 : ar.rv2));
  float* outp = (seg == 0 ? ar.o0 : (seg == 1 ? ar.o1 : ar.o2));

  const int arow0 = by << 7;
  const int tx = tid & 15, ty = tid >> 4;
  const int sr = tid >> 2, skq = tid & 3;

  const float* Ap = ar.A + (size_t)(arow0 + sr) * Dd + (skq << 2);
  const float* Bp = Wsel + (size_t)(lc0 + sr) * Dd + (skq << 2);

  float acc[2][4][2][4];
  #pragma unroll
  for (int a = 0; a < 2; ++a)
    #pragma unroll
    for (int i = 0; i < 4; ++i)
      #pragma unroll
      for (int c = 0; c < 2; ++c)
        #pragma unroll
        for (int j = 0; j < 4; ++j) acc[a][i][c][j] = 0.f;

  for (int k0 = 0; k0 < Dd; k0 += 16) {
    float4 a0 = *(const float4*)(Ap + k0);
    float4 a1 = *(const float4*)(Ap + (size_t)64 * Dd + k0);
    float4 b0 = *(const float4*)(Bp + k0);
    float4 b1 = *(const float4*)(Bp + (size_t)64 * Dd + k0);
    __syncthreads();  // prior compute readers done before overwrite
    As[skq*4+0][sr] = a0.x; As[skq*4+1][sr] = a0.y; As[skq*4+2][sr] = a0.z; As[skq*4+3][sr] = a0.w;
    As[skq*4+0][sr+64] = a1.x; As[skq*4+1][sr+64] = a1.y; As[skq*4+2][sr+64] = a1.z; As[skq*4+3][sr+64] = a1.w;
    Bs[skq*4+0][sr] = b0.x; Bs[skq*4+1][sr] = b0.y; Bs[skq*4+2][sr] = b0.z; Bs[skq*4+3][sr] = b0.w;
    Bs[skq*4+0][sr+64] = b1.x; Bs[skq*4+1][sr+64] = b1.y; Bs[skq*4+2][sr+64] = b1.z; Bs[skq*4+3][sr+64] = b1.w;
    __syncthreads();
    #pragma unroll
    for (int k = 0; k < 16; ++k) {
      float4 av0 = *(const float4*)&As[k][ty << 2];
      float4 av1 = *(const float4*)&As[k][64 + (ty << 2)];
      float4 bv0 = *(const float4*)&Bs[k][tx << 2];
      float4 bv1 = *(const float4*)&Bs[k][64 + (tx << 2)];
      const float aa[2][4] = {{av0.x, av0.y, av0.z, av0.w}, {av1.x, av1.y, av1.z, av1.w}};
      const float bb[2][4] = {{bv0.x, bv0.y, bv0.z, bv0.w}, {bv1.x, bv1.y, bv1.z, bv1.w}};
      #pragma unroll
      for (int rh = 0; rh < 2; ++rh)
        #pragma unroll
        for (int i = 0; i < 4; ++i)
          #pragma unroll
          for (int ch = 0; ch < 2; ++ch)
            #pragma unroll
            for (int j = 0; j < 4; ++j)
              acc[rh][i][ch][j] = fmaf(aa[rh][i], bb[ch][j], acc[rh][i][ch][j]);
    }
  }

  // Epilogue: per-column BN constants (f64 for stability), then op per segment.
  float scol[2][4], shcol[2][4];
  #pragma unroll
  for (int ch = 0; ch < 2; ++ch)
    #pragma unroll
    for (int j = 0; j < 4; ++j) {
      int c = lc0 + ch * 64 + (tx << 2) + j;
      double S = (double)gp[c] / sqrt((double)rvp[c] + 1e-5);
      double Sh = (double)bp[c] - (double)rmp[c] * S;
      if (MODE == 1) Sh += (double)ar.bias[c] * S;
      scol[ch][j] = (float)S; shcol[ch][j] = (float)Sh;
    }

  #pragma unroll
  for (int rh = 0; rh < 2; ++rh)
    #pragma unroll
    for (int i = 0; i < 4; ++i) {
      int r = arow0 + rh * 64 + (ty << 2) + i;
      #pragma unroll
      for (int ch = 0; ch < 2; ++ch) {
        float4 o;
        float* ov = &o.x;
        #pragma unroll
        for (int j = 0; j < 4; ++j) {
          float y = acc[rh][i][ch][j] * scol[ch][j] + shcol[ch][j];
          if (MODE == 0) {
            if (seg == 1) y = fmaxf(y, 0.f);
            else if (seg == 2) y = (y >= 1.f ? 1.f : 0.f) - (-y >= 1.f ? 1.f : 0.f);
          }
          ov[j] = y;
        }
        *(float4*)(outp + (size_t)r * Dd + lc0 + ch * 64 + (tx << 2)) = o;
      }
    }
}

// ---------------- LIF (in-place, scan over T=4) ----------------
// reset = H(mem_prev - 1); mem = 0.5*mem_prev + x - reset; spk = H(mem - 1)
__global__ void lif_k(float* __restrict__ buf) {
  const int N4 = Bb * Ll * Dd / 4;  // 524288
  int i = blockIdx.x * blockDim.x + threadIdx.x;
  if (i >= N4) return;
  const int PB = Ll * Dd / 4;  // 65536 float4 per (b,t)
  int b = i >> 16;
  int r = i & 65535;
  float4* p0 = (float4*)buf + (size_t)b * Tt * PB + r;
  float m0 = 0.f, m1 = 0.f, m2 = 0.f, m3 = 0.f;
  #pragma unroll
  for (int t = 0; t < Tt; ++t) {
    float4* p = p0 + (size_t)t * PB;
    float4 xv = *p;
    float4 s;
    { float rst = (m0 >= 1.f) ? 1.f : 0.f; m0 = 0.5f * m0 + xv.x - rst; s.x = (m0 >= 1.f) ? 1.f : 0.f; }
    { float rst = (m1 >= 1.f) ? 1.f : 0.f; m1 = 0.5f * m1 + xv.y - rst; s.y = (m1 >= 1.f) ? 1.f : 0.f; }
    { float rst = (m2 >= 1.f) ? 1.f : 0.f; m2 = 0.5f * m2 + xv.z - rst; s.z = (m2 >= 1.f) ? 1.f : 0.f; }
    { float rst = (m3 >= 1.f) ? 1.f : 0.f; m3 = 0.5f * m3 + xv.w - rst; s.w = (m3 >= 1.f) ? 1.f : 0.f; }
    *p = s;
  }
}

// ---------------- Attention: out = q @ (scale * (k^T v)) per (bt, h) ----------------
__global__ __launch_bounds__(256)
void attn_k(const float* __restrict__ qs, const float* __restrict__ ks,
            const float* __restrict__ vs, float* __restrict__ outp) {
  const int bt = blockIdx.x, h = blockIdx.y;
  const float* kp = ks + (size_t)bt * Ll * Dd + h * HDd;
  const float* vp = vs + (size_t)bt * Ll * Dd + h * HDd;
  const float* qp = qs + (size_t)bt * Ll * Dd + h * HDd;
  float* op = outp + (size_t)bt * Ll * Dd + h * HDd;

  __shared__ float KS[64][68];
  __shared__ float VS[64][68];
  __shared__ float G[64][68];

  const int tid = threadIdx.x;

  // ---- phase 1: G[e][d] = sum_m k[m][e] * v[m][d]
  const int te = tid & 15, td = tid >> 4;  // e-quad, d-quad
  float gacc[4][4];
  #pragma unroll
  for (int i = 0; i < 4; ++i)
    #pragma unroll
    for (int j = 0; j < 4; ++j) gacc[i][j] = 0.f;

  for (int m0 = 0; m0 < Ll; m0 += 64) {
    #pragma unroll
    for (int it = 0; it < 4; ++it) {
      int fidx = it * 256 + tid;
      int row = fidx >> 4, fq = fidx & 15;
      *(float4*)&KS[row][fq << 2] = *(const float4*)(kp + (size_t)(m0 + row) * Dd + (fq << 2));
      *(float4*)&VS[row][fq << 2] = *(const float4*)(vp + (size_t)(m0 + row) * Dd + (fq << 2));
    }
    __syncthreads();
    #pragma unroll 4
    for (int mm = 0; mm < 64; ++mm) {
      float4 k4 = *(const float4*)&KS[mm][te << 2];
      float4 v4 = *(const float4*)&VS[mm][td << 2];
      const float kk[4] = {k4.x, k4.y, k4.z, k4.w};
      const float vv[4] = {v4.x, v4.y, v4.z, v4.w};
      #pragma unroll
      for (int i = 0; i < 4; ++i)
        #pragma unroll
        for (int j = 0; j < 4; ++j)
          gacc[i][j] = fmaf(kk[i], vv[j], gacc[i][j]);
    }
    __syncthreads();
  }
  const float scl = 0.125f;  // HD^-0.5
  #pragma unroll
  for (int i = 0; i < 4; ++i)
    *(float4*)&G[(te << 2) + i][td << 2] =
        make_float4(gacc[i][0] * scl, gacc[i][1] * scl, gacc[i][2] * scl, gacc[i][3] * scl);
  __syncthreads();

  // ---- phase 2: out[l][d] = sum_e q[l][e] * G[e][d]   (q binary)
  const int lr = tid >> 2, dg = tid & 3;  // row-in-chunk, d-group of 16
  for (int l0 = 0; l0 < Ll; l0 += 64) {
    #pragma unroll
    for (int it = 0; it < 4; ++it) {
      int fidx = it * 256 + tid;
      int row = fidx >> 4, fq = fidx & 15;
      *(float4*)&KS[row][fq << 2] = *(const float4*)(qp + (size_t)(l0 + row) * Dd + (fq << 2));
    }
    __syncthreads();
    float oacc[16];
    #pragma unroll
    for (int j = 0; j < 16; ++j) oacc[j] = 0.f;
    for (int ee = 0; ee < 64; ++ee) {
      float qv = KS[lr][ee];
      #pragma unroll
      for (int jq = 0; jq < 4; ++jq) {
        float4 g4 = *(const float4*)&G[ee][(dg << 4) + (jq << 2)];
        oacc[jq * 4 + 0] = fmaf(qv, g4.x, oacc[jq * 4 + 0]);
        oacc[jq * 4 + 1] = fmaf(qv, g4.y, oacc[jq * 4 + 1]);
        oacc[jq * 4 + 2] = fmaf(qv, g4.z, oacc[jq * 4 + 2]);
        oacc[jq * 4 + 3] = fmaf(qv, g4.w, oacc[jq * 4 + 3]);
      }
    }
    #pragma unroll
    for (int jq = 0; jq < 4; ++jq)
      *(float4*)(op + (size_t)(l0 + lr) * Dd + (dg << 4) + (jq << 2)) =
          make_float4(oacc[jq * 4 + 0], oacc[jq * 4 + 1], oacc[jq * 4 + 2], oacc[jq * 4 + 3]);
    __syncthreads();
  }
}

// ---------------- launch ----------------
extern "C" void kernel_launch(void* const* d_in, const int* in_sizes, int n_in,
                              void* d_out, int out_size, void* d_ws, size_t ws_size,
                              hipStream_t stream) {
  const float* x    = (const float*)d_in[0];
  const float* q_w  = (const float*)d_in[1];
  const float* q_g  = (const float*)d_in[2];
  const float* q_b  = (const float*)d_in[3];
  const float* q_rm = (const float*)d_in[4];
  const float* q_rv = (const float*)d_in[5];
  const float* k_w  = (const float*)d_in[6];
  const float* k_g  = (const float*)d_in[7];
  const float* k_b  = (const float*)d_in[8];
  const float* k_rm = (const float*)d_in[9];
  const float* k_rv = (const float*)d_in[10];
  const float* v_w  = (const float*)d_in[11];
  const float* v_g  = (const float*)d_in[12];
  const float* v_b  = (const float*)d_in[13];
  const float* v_rm = (const float*)d_in[14];
  const float* v_rv = (const float*)d_in[15];
  const float* o_w  = (const float*)d_in[16];
  const float* o_bias = (const float*)d_in[17];
  const float* o_g  = (const float*)d_in[18];
  const float* o_b  = (const float*)d_in[19];
  const float* o_rm = (const float*)d_in[20];
  const float* o_rv = (const float*)d_in[21];

  float* ws = (float*)d_ws;
  const size_t NBUF = (size_t)Mm * Dd;  // 8388608
  float* q_lin = ws;               // q linear+BN, then LIF in-place -> spikes
  float* kbuf  = ws + NBUF;        // relu(BN(k))
  float* vbuf  = ws + 2 * NBUF;    // ternary v
  float* abuf  = ws + 3 * NBUF;    // attention output (B,T,L,D)
  float* obuf  = (float*)d_out;    // o linear+BN, then LIF in-place -> final spikes

  GemmArgs a1;
  a1.A = x;
  a1.W0 = q_w; a1.W1 = k_w; a1.W2 = v_w;
  a1.g0 = q_g; a1.b0 = q_b; a1.rm0 = q_rm; a1.rv0 = q_rv;
  a1.g1 = k_g; a1.b1 = k_b; a1.rm1 = k_rm; a1.rv1 = k_rv;
  a1.g2 = v_g; a1.b2 = v_b; a1.rm2 = v_rm; a1.rv2 = v_rv;
  a1.bias = nullptr;
  a1.o0 = q_lin; a1.o1 = kbuf; a1.o2 = vbuf;
  gemm_k<0><<<dim3(12, 128), 256, 0, stream>>>(a1);

  lif_k<<<2048, 256, 0, stream>>>(q_lin);

  attn_k<<<dim3(32, 8), 256, 0, stream>>>(q_lin, kbuf, vbuf, abuf);

  GemmArgs a2;
  a2.A = abuf;
  a2.W0 = o_w; a2.W1 = o_w; a2.W2 = o_w;
  a2.g0 = o_g; a2.b0 = o_b; a2.rm0 = o_rm; a2.rv0 = o_rv;
  a2.g1 = o_g; a2.b1 = o_b; a2.rm1 = o_rm; a2.rv1 = o_rv;
  a2.g2 = o_g; a2.b2 = o_b; a2.rm2 = o_rm; a2.rv2 = o_rv;
  a2.bias = o_bias;
  a2.o0 = obuf; a2.o1 = obuf; a2.o2 = obuf;
  gemm_k<1><<<dim3(4, 128), 256, 0, stream>>>(a2);

  lif_k<<<2048, 256, 0, stream>>>(obuf);
}

// Round 2
// 313.029 us; speedup vs baseline: 1.9412x; 1.9412x over previous
//
#include <hip/hip_runtime.h>
#include <math.h>
#include <stdint.h>

#define Bb 8
#define Tt 4
#define Ll 512
#define Dd 512
#define Hh 8
#define HDd 64
#define Mm (Bb*Tt*Ll)   // 16384 rows

typedef _Float16 f16;
typedef _Float16 f16x8 __attribute__((ext_vector_type(8)));
typedef float f32x4 __attribute__((ext_vector_type(4)));

#define LO_SCALE 2048.0f
#define LO_INV   4.8828125e-4f   // 1/2048 exact

__device__ __forceinline__ void gload16(const void* g, void* l) {
  __builtin_amdgcn_global_load_lds(
      (const __attribute__((address_space(1))) unsigned int*)(uintptr_t)g,
      (__attribute__((address_space(3))) unsigned int*)(uintptr_t)l,
      16, 0, 0);
}

// ---------------- split: f32 -> (hi f16, lo f16 scaled by 2048) ----------------
struct SplitArgs {
  const float* src[5];
  f16* hi[5];
  f16* lo[5];
};

// seg 0: x (8388608 elems = 1048576 groups of 8); segs 1..4: weights (262144 = 32768 groups)
__global__ void split_k(SplitArgs s) {
  int i = blockIdx.x * 256 + threadIdx.x;
  int seg, base;
  if (i < 1048576) { seg = 0; base = i; }
  else { int r = i - 1048576; seg = 1 + (r >> 15); base = r & 32767; }
  const float* sp = s.src[seg] + (size_t)base * 8;
  float4 v0 = *(const float4*)sp;
  float4 v1 = *(const float4*)(sp + 4);
  float a[8] = {v0.x, v0.y, v0.z, v0.w, v1.x, v1.y, v1.z, v1.w};
  f16x8 hv, lv;
  #pragma unroll
  for (int e = 0; e < 8; ++e) {
    f16 hh = (f16)a[e];
    hv[e] = hh;
    lv[e] = (f16)((a[e] - (float)hh) * LO_SCALE);
  }
  *(f16x8*)(s.hi[seg] + (size_t)base * 8) = hv;
  *(f16x8*)(s.lo[seg] + (size_t)base * 8) = lv;
}

// ---------------- f16x2 MFMA GEMM (m97 structure) ----------------
// C[m][n] = sum_k A[m][k]*W[n][k]; A split (Ah,Al), W split (Wh,Wl), lo scaled x2048.
// 128x128 tile, BK=32, 256 threads = 4 waves (2x2), wave tile 64x64 = 4x4 frags 16x16x32.
struct GArgs {
  const f16 *Ah, *Al;
  const f16 *Wh0, *Wl0, *Wh1, *Wl1, *Wh2, *Wl2;
  const float *g0,*b0,*rm0,*rv0;
  const float *g1,*b1,*rm1,*rv1;
  const float *g2,*b2,*rm2,*rv2;
  const float* bias;   // MODE==1 only
  float *o0, *o1, *o2;
};

// MODE 0: QKV fused (grid.x=12: 0-3 q-linear, 4-7 k-relu, 8-11 v-ternary)
// MODE 1: O-proj (grid.x=4): y = (acc + bias)*S + Sh
template<int MODE>
__global__ __launch_bounds__(256, 2)
void gemm_f16(GArgs ar) {
  __shared__ __align__(16) f16 Ah_s[4096];  // [128][32]
  __shared__ __align__(16) f16 Al_s[4096];
  __shared__ __align__(16) f16 Bh_s[4096];
  __shared__ __align__(16) f16 Bl_s[4096];

  const int tid = threadIdx.x;
  const int lane = tid & 63, wid = tid >> 6;
  const int bx = blockIdx.x, by = blockIdx.y;
  const int seg = (MODE == 0) ? (bx >> 2) : 0;
  const int lc0 = (MODE == 0) ? ((bx & 3) << 7) : (bx << 7);
  const int m0 = by << 7;

  const f16* Wh = (seg == 0 ? ar.Wh0 : (seg == 1 ? ar.Wh1 : ar.Wh2));
  const f16* Wl = (seg == 0 ? ar.Wl0 : (seg == 1 ? ar.Wl1 : ar.Wl2));
  const float* gp  = (seg == 0 ? ar.g0  : (seg == 1 ? ar.g1  : ar.g2));
  const float* bp  = (seg == 0 ? ar.b0  : (seg == 1 ? ar.b1  : ar.b2));
  const float* rmp = (seg == 0 ? ar.rm0 : (seg == 1 ? ar.rm1 : ar.rm2));
  const float* rvp = (seg == 0 ? ar.rv0 : (seg == 1 ? ar.rv1 : ar.rv2));
  float* outp = (seg == 0 ? ar.o0 : (seg == 1 ? ar.o1 : ar.o2));

  const int srow = lane >> 2, skc = lane & 3;      // staging: row-in-64, 16B chunk
  const int fr = lane & 15, kg = lane >> 4;        // fragment: row/col, k-group
  const int wmr = wid >> 1, wnc = wid & 1;         // wave 2x2

  f32x4 acc_h[4][4], acc_l[4][4];
  #pragma unroll
  for (int i = 0; i < 4; ++i)
    #pragma unroll
    for (int j = 0; j < 4; ++j) {
      acc_h[i][j] = (f32x4)0.0f;
      acc_l[i][j] = (f32x4)0.0f;
    }

  for (int k0 = 0; k0 < Dd; k0 += 32) {
    __syncthreads();   // readers of previous tile done
    #pragma unroll
    for (int i = 0; i < 2; ++i) {
      const int r = i * 64 + wid * 16 + srow;
      const size_t goA = (size_t)(m0 + r) * Dd + k0 + skc * 8;
      const size_t goB = (size_t)(lc0 + r) * Dd + k0 + skc * 8;
      const int lbase = i * 2048 + wid * 512;   // f16 units; + lane*8 done by HW
      gload16(ar.Ah + goA, Ah_s + lbase);
      gload16(ar.Al + goA, Al_s + lbase);
      gload16(Wh + goB, Bh_s + lbase);
      gload16(Wl + goB, Bl_s + lbase);
    }
    __syncthreads();   // compiler drains vmcnt before barrier

    f16x8 a_h[4], a_l[4], b_h[4], b_l[4];
    #pragma unroll
    for (int i = 0; i < 4; ++i) {
      const int ra = (wmr * 64 + i * 16 + fr) * 32 + kg * 8;
      a_h[i] = *(const f16x8*)&Ah_s[ra];
      a_l[i] = *(const f16x8*)&Al_s[ra];
      const int rb = (wnc * 64 + i * 16 + fr) * 32 + kg * 8;
      b_h[i] = *(const f16x8*)&Bh_s[rb];
      b_l[i] = *(const f16x8*)&Bl_s[rb];
    }
    #pragma unroll
    for (int i = 0; i < 4; ++i)
      #pragma unroll
      for (int j = 0; j < 4; ++j) {
        acc_h[i][j] = __builtin_amdgcn_mfma_f32_16x16x32_f16(a_h[i], b_h[j], acc_h[i][j], 0, 0, 0);
        acc_l[i][j] = __builtin_amdgcn_mfma_f32_16x16x32_f16(a_h[i], b_l[j], acc_l[i][j], 0, 0, 0);
        acc_l[i][j] = __builtin_amdgcn_mfma_f32_16x16x32_f16(a_l[i], b_h[j], acc_l[i][j], 0, 0, 0);
      }
  }

  // per-column BN constants (4 cols per thread: one per j-frag)
  float scl[4], shc[4];
  #pragma unroll
  for (int j = 0; j < 4; ++j) {
    const int c = lc0 + wnc * 64 + j * 16 + fr;
    double S = (double)gp[c] / sqrt((double)rvp[c] + 1e-5);
    double Sh = (double)bp[c] - (double)rmp[c] * S;
    if (MODE == 1) Sh += (double)ar.bias[c] * S;
    scl[j] = (float)S; shc[j] = (float)Sh;
  }

  #pragma unroll
  for (int i = 0; i < 4; ++i)
    #pragma unroll
    for (int r = 0; r < 4; ++r) {
      const int row = m0 + wmr * 64 + i * 16 + kg * 4 + r;
      #pragma unroll
      for (int j = 0; j < 4; ++j) {
        const int col = lc0 + wnc * 64 + j * 16 + fr;
        float val = acc_h[i][j][r] + acc_l[i][j][r] * LO_INV;
        float y = val * scl[j] + shc[j];
        if (MODE == 0) {
          if (seg == 1) y = fmaxf(y, 0.f);
          else if (seg == 2) y = (y >= 1.f ? 1.f : 0.f) - (-y >= 1.f ? 1.f : 0.f);
        }
        outp[(size_t)row * Dd + col] = y;
      }
    }
}

// ---------------- LIF (in-place, scan over T=4) ----------------
__global__ void lif_k(float* __restrict__ buf) {
  const int N4 = Bb * Ll * Dd / 4;
  int i = blockIdx.x * blockDim.x + threadIdx.x;
  if (i >= N4) return;
  const int PB = Ll * Dd / 4;
  int b = i >> 16;
  int r = i & 65535;
  float4* p0 = (float4*)buf + (size_t)b * Tt * PB + r;
  float m0 = 0.f, m1 = 0.f, m2 = 0.f, m3 = 0.f;
  #pragma unroll
  for (int t = 0; t < Tt; ++t) {
    float4* p = p0 + (size_t)t * PB;
    float4 xv = *p;
    float4 s;
    { float rst = (m0 >= 1.f) ? 1.f : 0.f; m0 = 0.5f * m0 + xv.x - rst; s.x = (m0 >= 1.f) ? 1.f : 0.f; }
    { float rst = (m1 >= 1.f) ? 1.f : 0.f; m1 = 0.5f * m1 + xv.y - rst; s.y = (m1 >= 1.f) ? 1.f : 0.f; }
    { float rst = (m2 >= 1.f) ? 1.f : 0.f; m2 = 0.5f * m2 + xv.z - rst; s.z = (m2 >= 1.f) ? 1.f : 0.f; }
    { float rst = (m3 >= 1.f) ? 1.f : 0.f; m3 = 0.5f * m3 + xv.w - rst; s.w = (m3 >= 1.f) ? 1.f : 0.f; }
    *p = s;
  }
}

// ---------------- attention phase 1: partial G = 0.125 * k^T v over 128-row m-chunk ----------------
__global__ __launch_bounds__(256)
void attn_g(const float* __restrict__ ks, const float* __restrict__ vs,
            float* __restrict__ pG) {
  const int bt = blockIdx.x, h = blockIdx.y, c = blockIdx.z;
  const float* kp = ks + (size_t)bt * Ll * Dd + h * HDd;
  const float* vp = vs + (size_t)bt * Ll * Dd + h * HDd;

  __shared__ float KS[64][68];
  __shared__ float VS[64][68];
  const int tid = threadIdx.x;
  const int te = tid & 15, td = tid >> 4;

  float gacc[4][4];
  #pragma unroll
  for (int i = 0; i < 4; ++i)
    #pragma unroll
    for (int j = 0; j < 4; ++j) gacc[i][j] = 0.f;

  for (int mt = 0; mt < 2; ++mt) {
    const int m0 = c * 128 + mt * 64;
    #pragma unroll
    for (int it = 0; it < 4; ++it) {
      int fidx = it * 256 + tid;
      int row = fidx >> 4, fq = fidx & 15;
      *(float4*)&KS[row][fq << 2] = *(const float4*)(kp + (size_t)(m0 + row) * Dd + (fq << 2));
      *(float4*)&VS[row][fq << 2] = *(const float4*)(vp + (size_t)(m0 + row) * Dd + (fq << 2));
    }
    __syncthreads();
    #pragma unroll 4
    for (int mm = 0; mm < 64; ++mm) {
      float4 k4 = *(const float4*)&KS[mm][te << 2];
      float4 v4 = *(const float4*)&VS[mm][td << 2];
      const float kk[4] = {k4.x, k4.y, k4.z, k4.w};
      const float vv[4] = {v4.x, v4.y, v4.z, v4.w};
      #pragma unroll
      for (int i = 0; i < 4; ++i)
        #pragma unroll
        for (int j = 0; j < 4; ++j)
          gacc[i][j] = fmaf(kk[i], vv[j], gacc[i][j]);
    }
    __syncthreads();
  }
  float* out = pG + (((size_t)(bt * 8 + h) * 4 + c) << 12);
  #pragma unroll
  for (int i = 0; i < 4; ++i)
    *(float4*)&out[((te << 2) + i) * 64 + (td << 2)] =
        make_float4(gacc[i][0] * 0.125f, gacc[i][1] * 0.125f,
                    gacc[i][2] * 0.125f, gacc[i][3] * 0.125f);
}

// ---------------- attention phase 2: out = q @ G, written as hi/lo f16 split ----------------
__global__ __launch_bounds__(256)
void attn_o(const float* __restrict__ qs, const float* __restrict__ pG,
            f16* __restrict__ ahi, f16* __restrict__ alo) {
  const int bt = blockIdx.x, h = blockIdx.y, lc = blockIdx.z;
  __shared__ float G[64][68];
  __shared__ float QS[64][68];
  const int tid = threadIdx.x;

  const float* pg = pG + (((size_t)(bt * 8 + h) * 4) << 12);
  #pragma unroll
  for (int rep = 0; rep < 4; ++rep) {
    int t4 = rep * 256 + tid;
    int e = t4 >> 4, dq = t4 & 15;
    int off = e * 64 + (dq << 2);
    float4 s0 = *(const float4*)(pg + off);
    float4 s1 = *(const float4*)(pg + 4096 + off);
    float4 s2 = *(const float4*)(pg + 8192 + off);
    float4 s3 = *(const float4*)(pg + 12288 + off);
    *(float4*)&G[e][dq << 2] = make_float4(s0.x + s1.x + s2.x + s3.x,
                                           s0.y + s1.y + s2.y + s3.y,
                                           s0.z + s1.z + s2.z + s3.z,
                                           s0.w + s1.w + s2.w + s3.w);
  }
  __syncthreads();

  const float* qp = qs + (size_t)bt * Ll * Dd + h * HDd;
  const int lr = tid >> 2, dg = tid & 3;

  for (int l0 = 0; l0 < 128; l0 += 64) {
    #pragma unroll
    for (int it = 0; it < 4; ++it) {
      int fidx = it * 256 + tid;
      int row = fidx >> 4, fq = fidx & 15;
      *(float4*)&QS[row][fq << 2] =
          *(const float4*)(qp + (size_t)(lc * 128 + l0 + row) * Dd + (fq << 2));
    }
    __syncthreads();
    float oacc[16];
    #pragma unroll
    for (int j = 0; j < 16; ++j) oacc[j] = 0.f;
    for (int ee = 0; ee < 64; ++ee) {
      float qv = QS[lr][ee];
      #pragma unroll
      for (int jq = 0; jq < 4; ++jq) {
        float4 g4 = *(const float4*)&G[ee][(dg << 4) + (jq << 2)];
        oacc[jq * 4 + 0] = fmaf(qv, g4.x, oacc[jq * 4 + 0]);
        oacc[jq * 4 + 1] = fmaf(qv, g4.y, oacc[jq * 4 + 1]);
        oacc[jq * 4 + 2] = fmaf(qv, g4.z, oacc[jq * 4 + 2]);
        oacc[jq * 4 + 3] = fmaf(qv, g4.w, oacc[jq * 4 + 3]);
      }
    }
    f16x8 h0, l0v, h1, l1v;
    #pragma unroll
    for (int t = 0; t < 8; ++t) {
      float v = oacc[t];
      f16 hh = (f16)v;
      h0[t] = hh; l0v[t] = (f16)((v - (float)hh) * LO_SCALE);
      float v2 = oacc[8 + t];
      f16 hh2 = (f16)v2;
      h1[t] = hh2; l1v[t] = (f16)((v2 - (float)hh2) * LO_SCALE);
    }
    size_t ob = ((size_t)bt * Ll + lc * 128 + l0 + lr) * Dd + h * HDd + (dg << 4);
    *(f16x8*)(ahi + ob) = h0;
    *(f16x8*)(ahi + ob + 8) = h1;
    *(f16x8*)(alo + ob) = l0v;
    *(f16x8*)(alo + ob + 8) = l1v;
    __syncthreads();
  }
}

// ---------------- launch ----------------
extern "C" void kernel_launch(void* const* d_in, const int* in_sizes, int n_in,
                              void* d_out, int out_size, void* d_ws, size_t ws_size,
                              hipStream_t stream) {
  const float* x    = (const float*)d_in[0];
  const float* q_w  = (const float*)d_in[1];
  const float* q_g  = (const float*)d_in[2];
  const float* q_b  = (const float*)d_in[3];
  const float* q_rm = (const float*)d_in[4];
  const float* q_rv = (const float*)d_in[5];
  const float* k_w  = (const float*)d_in[6];
  const float* k_g  = (const float*)d_in[7];
  const float* k_b  = (const float*)d_in[8];
  const float* k_rm = (const float*)d_in[9];
  const float* k_rv = (const float*)d_in[10];
  const float* v_w  = (const float*)d_in[11];
  const float* v_g  = (const float*)d_in[12];
  const float* v_b  = (const float*)d_in[13];
  const float* v_rm = (const float*)d_in[14];
  const float* v_rv = (const float*)d_in[15];
  const float* o_w  = (const float*)d_in[16];
  const float* o_bias = (const float*)d_in[17];
  const float* o_g  = (const float*)d_in[18];
  const float* o_b  = (const float*)d_in[19];
  const float* o_rm = (const float*)d_in[20];
  const float* o_rv = (const float*)d_in[21];

  float* ws = (float*)d_ws;
  const size_t NBUF = (size_t)Mm * Dd;  // 8388608 elements
  float* q_lin = ws;                    // f32; LIF in-place -> q spikes
  float* kbuf  = ws + NBUF;             // f32 relu(BN(k)); later ahi/alo region
  float* vbuf  = ws + 2 * NBUF;         // f32 ternary v
  float* reg3  = ws + 3 * NBUF;         // xhi+xlo f16; later pG f32 (16.8MB)
  f16* xhi = (f16*)reg3;
  f16* xlo = xhi + NBUF;
  float* pG = reg3;                     // 32*8*4*4096 f32 = 16.8MB (overlays xhi)
  f16* wsp = (f16*)(ws + 4 * NBUF);     // 8 x 262144 f16 = 4MB
  f16* qwh = wsp;            f16* qwl = wsp + 262144;
  f16* kwh = wsp + 2*262144; f16* kwl = wsp + 3*262144;
  f16* vwh = wsp + 4*262144; f16* vwl = wsp + 5*262144;
  f16* owh = wsp + 6*262144; f16* owl = wsp + 7*262144;
  f16* ahi = (f16*)kbuf;
  f16* alo = ahi + NBUF;
  float* obuf = (float*)d_out;

  SplitArgs sa;
  sa.src[0] = x;   sa.hi[0] = xhi; sa.lo[0] = xlo;
  sa.src[1] = q_w; sa.hi[1] = qwh; sa.lo[1] = qwl;
  sa.src[2] = k_w; sa.hi[2] = kwh; sa.lo[2] = kwl;
  sa.src[3] = v_w; sa.hi[3] = vwh; sa.lo[3] = vwl;
  sa.src[4] = o_w; sa.hi[4] = owh; sa.lo[4] = owl;
  split_k<<<4608, 256, 0, stream>>>(sa);

  GArgs a1;
  a1.Ah = xhi; a1.Al = xlo;
  a1.Wh0 = qwh; a1.Wl0 = qwl; a1.Wh1 = kwh; a1.Wl1 = kwl; a1.Wh2 = vwh; a1.Wl2 = vwl;
  a1.g0 = q_g; a1.b0 = q_b; a1.rm0 = q_rm; a1.rv0 = q_rv;
  a1.g1 = k_g; a1.b1 = k_b; a1.rm1 = k_rm; a1.rv1 = k_rv;
  a1.g2 = v_g; a1.b2 = v_b; a1.rm2 = v_rm; a1.rv2 = v_rv;
  a1.bias = nullptr;
  a1.o0 = q_lin; a1.o1 = kbuf; a1.o2 = vbuf;
  gemm_f16<0><<<dim3(12, 128), 256, 0, stream>>>(a1);

  lif_k<<<2048, 256, 0, stream>>>(q_lin);

  attn_g<<<dim3(32, 8, 4), 256, 0, stream>>>(kbuf, vbuf, pG);
  attn_o<<<dim3(32, 8, 4), 256, 0, stream>>>(q_lin, pG, ahi, alo);

  GArgs a2;
  a2.Ah = ahi; a2.Al = alo;
  a2.Wh0 = owh; a2.Wl0 = owl; a2.Wh1 = owh; a2.Wl1 = owl; a2.Wh2 = owh; a2.Wl2 = owl;
  a2.g0 = o_g; a2.b0 = o_b; a2.rm0 = o_rm; a2.rv0 = o_rv;
  a2.g1 = o_g; a2.b1 = o_b; a2.rm1 = o_rm; a2.rv1 = o_rv;
  a2.g2 = o_g; a2.b2 = o_b; a2.rm2 = o_rm; a2.rv2 = o_rv;
  a2.bias = o_bias;
  a2.o0 = obuf; a2.o1 = obuf; a2.o2 = obuf;
  gemm_f16<1><<<dim3(4, 128), 256, 0, stream>>>(a2);

  lif_k<<<2048, 256, 0, stream>>>(obuf);
}

// Round 3
// 302.585 us; speedup vs baseline: 2.0082x; 1.0345x over previous
//
#include <hip/hip_runtime.h>
#include <math.h>
#include <stdint.h>

#define Bb 8
#define Tt 4
#define Ll 512
#define Dd 512
#define Hh 8
#define HDd 64
#define Mm (Bb*Tt*Ll)   // 16384 rows

typedef _Float16 f16;
typedef _Float16 f16x8 __attribute__((ext_vector_type(8)));
typedef _Float16 f16x4 __attribute__((ext_vector_type(4)));
typedef float f32x4 __attribute__((ext_vector_type(4)));

#define LO_SCALE 2048.0f
#define LO_INV   4.8828125e-4f   // 1/2048 exact

__device__ __forceinline__ void gload16(const void* g, void* l) {
  __builtin_amdgcn_global_load_lds(
      (const __attribute__((address_space(1))) unsigned int*)(uintptr_t)g,
      (__attribute__((address_space(3))) unsigned int*)(uintptr_t)l,
      16, 0, 0);
}

// ---------------- split: f32 -> (hi f16, lo f16 scaled by 2048) ----------------
struct SplitArgs {
  const float* src[5];
  f16* hi[5];
  f16* lo[5];
};

__global__ void split_k(SplitArgs s) {
  int i = blockIdx.x * 256 + threadIdx.x;
  int seg, base;
  if (i < 1048576) { seg = 0; base = i; }
  else { int r = i - 1048576; seg = 1 + (r >> 15); base = r & 32767; }
  const float* sp = s.src[seg] + (size_t)base * 8;
  float4 v0 = *(const float4*)sp;
  float4 v1 = *(const float4*)(sp + 4);
  float a[8] = {v0.x, v0.y, v0.z, v0.w, v1.x, v1.y, v1.z, v1.w};
  f16x8 hv, lv;
  #pragma unroll
  for (int e = 0; e < 8; ++e) {
    f16 hh = (f16)a[e];
    hv[e] = hh;
    lv[e] = (f16)((a[e] - (float)hh) * LO_SCALE);
  }
  *(f16x8*)(s.hi[seg] + (size_t)base * 8) = hv;
  *(f16x8*)(s.lo[seg] + (size_t)base * 8) = lv;
}

// ---------------- f16x2 MFMA GEMM with fused BN + LIF epilogues ----------------
// Row mapping: by in [0,128): b = by>>4, lc32 = by&15.
// tile_row r in [0,128): t = r>>5, rl = r&31; global row = (b*4+t)*512 + lc32*32 + rl.
// This gives each tile all 4 timesteps of 32 l-values -> LIF scan fusable in epilogue.
struct GArgs {
  const f16 *Ah, *Al;
  const f16 *Wh0, *Wl0, *Wh1, *Wl1, *Wh2, *Wl2;
  const float *g0,*b0,*rm0,*rv0;
  const float *g1,*b1,*rm1,*rv1;
  const float *g2,*b2,*rm2,*rv2;
  const float* bias;   // MODE==1 only
  f16*   oq;   // MODE0 seg0: q spikes (f16 exact {0,1})
  float* ok;   // MODE0 seg1: relu(BN(k)) f32
  f16*   ov;   // MODE0 seg2: ternary v (f16 exact {-1,0,1})
  float* oo;   // MODE1: final spikes f32 (d_out)
};

#define SMEM_BYTES 34048   // max(4*8192 staging, 64*133*4 TS)

template<int MODE>
__global__ __launch_bounds__(256, 2)
void gemm_f16(GArgs ar) {
  extern __shared__ __align__(16) char smem[];
  f16* Ah_s = (f16*)smem;                  // [128][32] = 8192 B
  f16* Al_s = (f16*)(smem + 8192);
  f16* Bh_s = (f16*)(smem + 16384);
  f16* Bl_s = (f16*)(smem + 24576);
  float (*TS)[133] = (float(*)[133])smem;  // [64 cols][128 rows + pad] (reuses staging)

  const int tid = threadIdx.x;
  const int lane = tid & 63, wid = tid >> 6;
  const int bx = blockIdx.x, by = blockIdx.y;
  const int seg = (MODE == 0) ? (bx >> 2) : 0;
  const int lc0 = (MODE == 0) ? ((bx & 3) << 7) : (bx << 7);
  const int b = by >> 4, lc32 = by & 15;

  const f16* Wh = (seg == 0 ? ar.Wh0 : (seg == 1 ? ar.Wh1 : ar.Wh2));
  const f16* Wl = (seg == 0 ? ar.Wl0 : (seg == 1 ? ar.Wl1 : ar.Wl2));
  const float* gp  = (seg == 0 ? ar.g0  : (seg == 1 ? ar.g1  : ar.g2));
  const float* bp  = (seg == 0 ? ar.b0  : (seg == 1 ? ar.b1  : ar.b2));
  const float* rmp = (seg == 0 ? ar.rm0 : (seg == 1 ? ar.rm1 : ar.rm2));
  const float* rvp = (seg == 0 ? ar.rv0 : (seg == 1 ? ar.rv1 : ar.rv2));

  const int srow = lane >> 2, skc = lane & 3;      // staging: row-in-16-group, 16B chunk
  const int fr = lane & 15, kg = lane >> 4;        // fragment: row/col, k-group
  const int wmr = wid >> 1, wnc = wid & 1;         // wave 2x2

  f32x4 acc_h[4][4], acc_l[4][4];
  #pragma unroll
  for (int i = 0; i < 4; ++i)
    #pragma unroll
    for (int j = 0; j < 4; ++j) {
      acc_h[i][j] = (f32x4)0.0f;
      acc_l[i][j] = (f32x4)0.0f;
    }

  for (int k0 = 0; k0 < Dd; k0 += 32) {
    __syncthreads();   // readers of previous tile done
    #pragma unroll
    for (int i = 0; i < 2; ++i) {
      const int r = i * 64 + wid * 16 + srow;
      const int grow = (((b << 2) + (r >> 5)) << 9) + (lc32 << 5) + (r & 31);
      const size_t goA = (size_t)grow * Dd + k0 + skc * 8;
      const size_t goB = (size_t)(lc0 + r) * Dd + k0 + skc * 8;
      const int lbase = i * 2048 + wid * 512;   // f16 units; + lane*8 done by HW
      gload16(ar.Ah + goA, Ah_s + lbase);
      gload16(ar.Al + goA, Al_s + lbase);
      gload16(Wh + goB, Bh_s + lbase);
      gload16(Wl + goB, Bl_s + lbase);
    }
    __syncthreads();   // compiler drains vmcnt before barrier

    f16x8 a_h[4], a_l[4], b_h[4], b_l[4];
    #pragma unroll
    for (int i = 0; i < 4; ++i) {
      const int ra = (wmr * 64 + i * 16 + fr) * 32 + kg * 8;
      a_h[i] = *(const f16x8*)&Ah_s[ra];
      a_l[i] = *(const f16x8*)&Al_s[ra];
      const int rb = (wnc * 64 + i * 16 + fr) * 32 + kg * 8;
      b_h[i] = *(const f16x8*)&Bh_s[rb];
      b_l[i] = *(const f16x8*)&Bl_s[rb];
    }
    #pragma unroll
    for (int i = 0; i < 4; ++i)
      #pragma unroll
      for (int j = 0; j < 4; ++j) {
        acc_h[i][j] = __builtin_amdgcn_mfma_f32_16x16x32_f16(a_h[i], b_h[j], acc_h[i][j], 0, 0, 0);
        acc_l[i][j] = __builtin_amdgcn_mfma_f32_16x16x32_f16(a_h[i], b_l[j], acc_l[i][j], 0, 0, 0);
        acc_l[i][j] = __builtin_amdgcn_mfma_f32_16x16x32_f16(a_l[i], b_h[j], acc_l[i][j], 0, 0, 0);
      }
  }

  // per-column BN constants (4 cols per thread: one per j-frag)
  float scl[4], shc[4];
  #pragma unroll
  for (int j = 0; j < 4; ++j) {
    const int c = lc0 + wnc * 64 + j * 16 + fr;
    double S = (double)gp[c] / sqrt((double)rvp[c] + 1e-5);
    double Sh = (double)bp[c] - (double)rmp[c] * S;
    if (MODE == 1) Sh += (double)ar.bias[c] * S;
    scl[j] = (float)S; shc[j] = (float)Sh;
  }

  if (MODE == 0 && seg != 0) {
    // direct-write path (k: relu f32, v: ternary f16)
    #pragma unroll
    for (int i = 0; i < 4; ++i)
      #pragma unroll
      for (int r = 0; r < 4; ++r) {
        const int tr = wmr * 64 + i * 16 + (kg << 2) + r;
        const int grow = (((b << 2) + (tr >> 5)) << 9) + (lc32 << 5) + (tr & 31);
        #pragma unroll
        for (int j = 0; j < 4; ++j) {
          const int col = lc0 + wnc * 64 + j * 16 + fr;
          float val = acc_h[i][j][r] + acc_l[i][j][r] * LO_INV;
          float y = val * scl[j] + shc[j];
          if (seg == 1) ar.ok[(size_t)grow * Dd + col] = fmaxf(y, 0.f);
          else ar.ov[(size_t)grow * Dd + col] =
                   (f16)((y >= 1.f ? 1.f : 0.f) - (-y >= 1.f ? 1.f : 0.f));
        }
      }
    return;
  }

  // fused BN + LIF epilogue (q spikes f16 / final spikes f32), one 64-col half at a time
  __syncthreads();  // all LDS fragment reads done; safe to reuse smem as TS
  #pragma unroll
  for (int half = 0; half < 2; ++half) {
    if (wnc == half) {
      #pragma unroll
      for (int i = 0; i < 4; ++i)
        #pragma unroll
        for (int j = 0; j < 4; ++j) {
          float4 yv;
          float* yp = &yv.x;
          #pragma unroll
          for (int r = 0; r < 4; ++r) {
            float val = acc_h[i][j][r] + acc_l[i][j][r] * LO_INV;
            yp[r] = val * scl[j] + shc[j];
          }
          *(float4*)&TS[j * 16 + fr][wmr * 64 + i * 16 + (kg << 2)] = yv;
        }
    }
    __syncthreads();
    const int cc4 = (tid & 15) << 2;
    #pragma unroll
    for (int rr = 0; rr < 2; ++rr) {
      const int rl = (tid >> 4) + (rr << 4);
      float mm[4] = {0.f, 0.f, 0.f, 0.f};
      #pragma unroll
      for (int t = 0; t < 4; ++t) {
        const int trow = t * 32 + rl;
        float sp[4];
        #pragma unroll
        for (int c = 0; c < 4; ++c) {
          float y = TS[cc4 + c][trow];
          float rst = (mm[c] >= 1.f) ? 1.f : 0.f;
          mm[c] = 0.5f * mm[c] + y - rst;
          sp[c] = (mm[c] >= 1.f) ? 1.f : 0.f;
        }
        const size_t go = ((size_t)((((b << 2) + t) << 9) + (lc32 << 5) + rl)) * Dd
                          + lc0 + (half << 6) + cc4;
        if (MODE == 0) {
          f16x4 s4;
          s4[0] = (f16)sp[0]; s4[1] = (f16)sp[1]; s4[2] = (f16)sp[2]; s4[3] = (f16)sp[3];
          *(f16x4*)(ar.oq + go) = s4;
        } else {
          *(float4*)(ar.oo + go) = make_float4(sp[0], sp[1], sp[2], sp[3]);
        }
      }
    }
    __syncthreads();
  }
}

// ---------------- attention phase 1: partial G = 0.125 * k^T v (k f32, v f16) ----------------
__global__ __launch_bounds__(256)
void attn_g(const float* __restrict__ ks, const f16* __restrict__ vs,
            float* __restrict__ pG) {
  const int bt = blockIdx.x, h = blockIdx.y, c = blockIdx.z;
  const float* kp = ks + (size_t)bt * Ll * Dd + h * HDd;
  const f16* vp = vs + (size_t)bt * Ll * Dd + h * HDd;

  __shared__ float KS[64][68];
  __shared__ float VS[64][68];
  const int tid = threadIdx.x;
  const int te = tid & 15, td = tid >> 4;

  float gacc[4][4];
  #pragma unroll
  for (int i = 0; i < 4; ++i)
    #pragma unroll
    for (int j = 0; j < 4; ++j) gacc[i][j] = 0.f;

  for (int mt = 0; mt < 2; ++mt) {
    const int m0 = c * 128 + mt * 64;
    #pragma unroll
    for (int it = 0; it < 4; ++it) {
      int fidx = it * 256 + tid;
      int row = fidx >> 4, fq = fidx & 15;
      *(float4*)&KS[row][fq << 2] = *(const float4*)(kp + (size_t)(m0 + row) * Dd + (fq << 2));
    }
    #pragma unroll
    for (int it = 0; it < 2; ++it) {
      int fidx = it * 256 + tid;     // [0,512)
      int row = fidx >> 3, c8 = fidx & 7;
      f16x8 hv = *(const f16x8*)(vp + (size_t)(m0 + row) * Dd + (c8 << 3));
      *(float4*)&VS[row][c8 << 3] = make_float4(hv[0], hv[1], hv[2], hv[3]);
      *(float4*)&VS[row][(c8 << 3) + 4] = make_float4(hv[4], hv[5], hv[6], hv[7]);
    }
    __syncthreads();
    #pragma unroll 4
    for (int mm = 0; mm < 64; ++mm) {
      float4 k4 = *(const float4*)&KS[mm][te << 2];
      float4 v4 = *(const float4*)&VS[mm][td << 2];
      const float kk[4] = {k4.x, k4.y, k4.z, k4.w};
      const float vv[4] = {v4.x, v4.y, v4.z, v4.w};
      #pragma unroll
      for (int i = 0; i < 4; ++i)
        #pragma unroll
        for (int j = 0; j < 4; ++j)
          gacc[i][j] = fmaf(kk[i], vv[j], gacc[i][j]);
    }
    __syncthreads();
  }
  float* out = pG + (((size_t)(bt * 8 + h) * 4 + c) << 12);
  #pragma unroll
  for (int i = 0; i < 4; ++i)
    *(float4*)&out[((te << 2) + i) * 64 + (td << 2)] =
        make_float4(gacc[i][0] * 0.125f, gacc[i][1] * 0.125f,
                    gacc[i][2] * 0.125f, gacc[i][3] * 0.125f);
}

// ---------------- attention phase 2: out = q @ G (q f16 spikes), hi/lo f16 output ----------------
__global__ __launch_bounds__(256)
void attn_o(const f16* __restrict__ qs, const float* __restrict__ pG,
            f16* __restrict__ ahi, f16* __restrict__ alo) {
  const int bt = blockIdx.x, h = blockIdx.y, lc = blockIdx.z;
  __shared__ float G[64][68];
  __shared__ float QS[64][68];
  const int tid = threadIdx.x;

  const float* pg = pG + (((size_t)(bt * 8 + h) * 4) << 12);
  #pragma unroll
  for (int rep = 0; rep < 4; ++rep) {
    int t4 = rep * 256 + tid;
    int e = t4 >> 4, dq = t4 & 15;
    int off = e * 64 + (dq << 2);
    float4 s0 = *(const float4*)(pg + off);
    float4 s1 = *(const float4*)(pg + 4096 + off);
    float4 s2 = *(const float4*)(pg + 8192 + off);
    float4 s3 = *(const float4*)(pg + 12288 + off);
    *(float4*)&G[e][dq << 2] = make_float4(s0.x + s1.x + s2.x + s3.x,
                                           s0.y + s1.y + s2.y + s3.y,
                                           s0.z + s1.z + s2.z + s3.z,
                                           s0.w + s1.w + s2.w + s3.w);
  }
  __syncthreads();

  const f16* qp = qs + (size_t)bt * Ll * Dd + h * HDd;
  const int lr = tid >> 2, dg = tid & 3;

  for (int l0 = 0; l0 < 128; l0 += 64) {
    #pragma unroll
    for (int it = 0; it < 2; ++it) {
      int fidx = it * 256 + tid;
      int row = fidx >> 3, c8 = fidx & 7;
      f16x8 hv = *(const f16x8*)(qp + (size_t)(lc * 128 + l0 + row) * Dd + (c8 << 3));
      *(float4*)&QS[row][c8 << 3] = make_float4(hv[0], hv[1], hv[2], hv[3]);
      *(float4*)&QS[row][(c8 << 3) + 4] = make_float4(hv[4], hv[5], hv[6], hv[7]);
    }
    __syncthreads();
    float oacc[16];
    #pragma unroll
    for (int j = 0; j < 16; ++j) oacc[j] = 0.f;
    for (int ee = 0; ee < 64; ++ee) {
      float qv = QS[lr][ee];
      #pragma unroll
      for (int jq = 0; jq < 4; ++jq) {
        float4 g4 = *(const float4*)&G[ee][(dg << 4) + (jq << 2)];
        oacc[jq * 4 + 0] = fmaf(qv, g4.x, oacc[jq * 4 + 0]);
        oacc[jq * 4 + 1] = fmaf(qv, g4.y, oacc[jq * 4 + 1]);
        oacc[jq * 4 + 2] = fmaf(qv, g4.z, oacc[jq * 4 + 2]);
        oacc[jq * 4 + 3] = fmaf(qv, g4.w, oacc[jq * 4 + 3]);
      }
    }
    f16x8 h0, l0v, h1, l1v;
    #pragma unroll
    for (int t = 0; t < 8; ++t) {
      float v = oacc[t];
      f16 hh = (f16)v;
      h0[t] = hh; l0v[t] = (f16)((v - (float)hh) * LO_SCALE);
      float v2 = oacc[8 + t];
      f16 hh2 = (f16)v2;
      h1[t] = hh2; l1v[t] = (f16)((v2 - (float)hh2) * LO_SCALE);
    }
    size_t ob = ((size_t)bt * Ll + lc * 128 + l0 + lr) * Dd + h * HDd + (dg << 4);
    *(f16x8*)(ahi + ob) = h0;
    *(f16x8*)(ahi + ob + 8) = h1;
    *(f16x8*)(alo + ob) = l0v;
    *(f16x8*)(alo + ob + 8) = l1v;
    __syncthreads();
  }
}

// ---------------- launch ----------------
extern "C" void kernel_launch(void* const* d_in, const int* in_sizes, int n_in,
                              void* d_out, int out_size, void* d_ws, size_t ws_size,
                              hipStream_t stream) {
  const float* x    = (const float*)d_in[0];
  const float* q_w  = (const float*)d_in[1];
  const float* q_g  = (const float*)d_in[2];
  const float* q_b  = (const float*)d_in[3];
  const float* q_rm = (const float*)d_in[4];
  const float* q_rv = (const float*)d_in[5];
  const float* k_w  = (const float*)d_in[6];
  const float* k_g  = (const float*)d_in[7];
  const float* k_b  = (const float*)d_in[8];
  const float* k_rm = (const float*)d_in[9];
  const float* k_rv = (const float*)d_in[10];
  const float* v_w  = (const float*)d_in[11];
  const float* v_g  = (const float*)d_in[12];
  const float* v_b  = (const float*)d_in[13];
  const float* v_rm = (const float*)d_in[14];
  const float* v_rv = (const float*)d_in[15];
  const float* o_w  = (const float*)d_in[16];
  const float* o_bias = (const float*)d_in[17];
  const float* o_g  = (const float*)d_in[18];
  const float* o_b  = (const float*)d_in[19];
  const float* o_rm = (const float*)d_in[20];
  const float* o_rv = (const float*)d_in[21];

  char* wsb = (char*)d_ws;
  const size_t R16 = 16777216;            // 16 MB = one NBUF of f16
  f16*   xhi  = (f16*)wsb;                // dead after QKV -> reused as ahi
  f16*   xlo  = (f16*)(wsb + R16);        // dead after QKV -> reused as alo
  f16*   qspk = (f16*)(wsb + 2 * R16);    // q spikes f16
  float* kbuf = (float*)(wsb + 3 * R16);  // relu(BN(k)) f32 (2 regions)
  f16*   vbuf = (f16*)(wsb + 5 * R16);    // ternary v f16
  float* pG   = (float*)(wsb + 6 * R16);  // partial G f32
  f16*   wsp  = (f16*)(wsb + 7 * R16);    // 8 x 262144 f16 = 4 MB weight splits
  f16* qwh = wsp;            f16* qwl = wsp + 262144;
  f16* kwh = wsp + 2*262144; f16* kwl = wsp + 3*262144;
  f16* vwh = wsp + 4*262144; f16* vwl = wsp + 5*262144;
  f16* owh = wsp + 6*262144; f16* owl = wsp + 7*262144;
  f16* ahi = xhi;
  f16* alo = xlo;

  SplitArgs sa;
  sa.src[0] = x;   sa.hi[0] = xhi; sa.lo[0] = xlo;
  sa.src[1] = q_w; sa.hi[1] = qwh; sa.lo[1] = qwl;
  sa.src[2] = k_w; sa.hi[2] = kwh; sa.lo[2] = kwl;
  sa.src[3] = v_w; sa.hi[3] = vwh; sa.lo[3] = vwl;
  sa.src[4] = o_w; sa.hi[4] = owh; sa.lo[4] = owl;
  split_k<<<4608, 256, 0, stream>>>(sa);

  GArgs a1;
  a1.Ah = xhi; a1.Al = xlo;
  a1.Wh0 = qwh; a1.Wl0 = qwl; a1.Wh1 = kwh; a1.Wl1 = kwl; a1.Wh2 = vwh; a1.Wl2 = vwl;
  a1.g0 = q_g; a1.b0 = q_b; a1.rm0 = q_rm; a1.rv0 = q_rv;
  a1.g1 = k_g; a1.b1 = k_b; a1.rm1 = k_rm; a1.rv1 = k_rv;
  a1.g2 = v_g; a1.b2 = v_b; a1.rm2 = v_rm; a1.rv2 = v_rv;
  a1.bias = nullptr;
  a1.oq = qspk; a1.ok = kbuf; a1.ov = vbuf; a1.oo = nullptr;
  gemm_f16<0><<<dim3(12, 128), 256, SMEM_BYTES, stream>>>(a1);

  attn_g<<<dim3(32, 8, 4), 256, 0, stream>>>(kbuf, vbuf, pG);
  attn_o<<<dim3(32, 8, 4), 256, 0, stream>>>(qspk, pG, ahi, alo);

  GArgs a2;
  a2.Ah = ahi; a2.Al = alo;
  a2.Wh0 = owh; a2.Wl0 = owl; a2.Wh1 = owh; a2.Wl1 = owl; a2.Wh2 = owh; a2.Wl2 = owl;
  a2.g0 = o_g; a2.b0 = o_b; a2.rm0 = o_rm; a2.rv0 = o_rv;
  a2.g1 = o_g; a2.b1 = o_b; a2.rm1 = o_rm; a2.rv1 = o_rv;
  a2.g2 = o_g; a2.b2 = o_b; a2.rm2 = o_rm; a2.rv2 = o_rv;
  a2.bias = o_bias;
  a2.oq = nullptr; a2.ok = nullptr; a2.ov = nullptr; a2.oo = (float*)d_out;
  gemm_f16<1><<<dim3(4, 128), 256, SMEM_BYTES, stream>>>(a2);
}